// Round 5
// baseline (2419.382 us; speedup 1.0000x reference)
//
#include <hip/hip_runtime.h>

#define WAVE 64
#define CDIV(a,b) (((a)+(b)-1)/(b))

typedef float f32x16 __attribute__((ext_vector_type(16)));
typedef unsigned short u16x8 __attribute__((ext_vector_type(8)));

// ---------- bf16 helpers: hi = truncate, lo = rne(residual) ----------
__device__ __forceinline__ unsigned short f2bf_rne(float f) {
    unsigned u = __float_as_uint(f);
    unsigned r = (u + 0x7FFFu + ((u >> 16) & 1u)) >> 16;
    return (unsigned short)r;
}
__device__ __forceinline__ float bf2f(unsigned short h) {
    return __uint_as_float(((unsigned)h) << 16);
}

#define MFMA32(acc, a, b) \
    asm volatile("v_mfma_f32_32x32x16_bf16 %0, %1, %2, %0" : "+v"(acc) : "v"(a), "v"(b))

// ---------- monotonic float<->uint encoding for atomicMax on floats ----------
__device__ __forceinline__ unsigned f2mono(float f) {
    unsigned u = __float_as_uint(f);
    return (u & 0x80000000u) ? ~u : (u | 0x80000000u);
}
__device__ __forceinline__ float mono2f(unsigned u) {
    return (u & 0x80000000u) ? __uint_as_float(u & 0x7fffffffu) : __uint_as_float(~u);
}
__device__ __forceinline__ float leaky(float v) { return (v > 0.0f) ? v : 0.01f*v; }

// =========================================================================
// k_cvt: f32 [rows][K] (stride ld) -> packed bf16 hi/lo [rows][Kp], k-pad zeroed
// =========================================================================
__global__ void k_cvt(const float* __restrict__ src, long ld, int rows, int K, int Kp,
                      unsigned short* __restrict__ hi, unsigned short* __restrict__ lo)
{
    int nc4 = Kp >> 2;
    long idx = (long)blockIdx.x*blockDim.x + threadIdx.x;
    if (idx >= (long)rows * nc4) return;
    long r = idx / nc4; int k = (int)(idx % nc4) << 2;
    float4 v = {0.0f, 0.0f, 0.0f, 0.0f};
    if (k + 4 <= K) v = *(const float4*)(src + r*ld + k);
    float vv[4] = {v.x, v.y, v.z, v.w};
    ushort4 h, l;
    unsigned short hh[4], ll[4];
    #pragma unroll
    for (int i = 0; i < 4; ++i) {
        unsigned u = __float_as_uint(vv[i]);
        hh[i] = (unsigned short)(u >> 16);
        ll[i] = f2bf_rne(vv[i] - bf2f(hh[i]));
    }
    h.x = hh[0]; h.y = hh[1]; h.z = hh[2]; h.w = hh[3];
    l.x = ll[0]; l.y = ll[1]; l.z = ll[2]; l.w = ll[3];
    *(ushort4*)(hi + r*Kp + k) = h;
    *(ushort4*)(lo + r*Kp + k) = l;
}

// =========================================================================
// k_gemm_pre: C[M,N'] = A[M,Kp] * B[N',Kp]^T on pre-split bf16 hi/lo.
// Block: 256 thr = 4 waves, tile 128 rows x 128 cols (grid.y = col block).
// Staging: thread t<128 -> A row t; t>=128 -> B row (t-128). 1 row/thread,
// guard-free (Kp padded, arrays padded). 2-deep register prefetch,
// double-buffered LDS in fragment order (conflict-free b128 both sides).
// bf16x3: AhBh + AlBh + AhBl  (~fp32 accuracy).
// =========================================================================
__global__ __launch_bounds__(256, 3)
void k_gemm_pre(const unsigned short* __restrict__ Ahi, const unsigned short* __restrict__ Alo,
                const unsigned short* __restrict__ Bhi, const unsigned short* __restrict__ Blo,
                float* __restrict__ C, long ldc, int M, int N, int Kp)
{
    __shared__ __align__(16) unsigned short Ah[2][4][64][8], Al[2][4][64][8];
    __shared__ __align__(16) unsigned short Bh[2][4][64][8], Bl[2][4][64][8];

    const int tid  = threadIdx.x;
    const int lane = tid & 63;
    const int wid  = tid >> 6;              // rowtile 0..3
    const int row0 = blockIdx.x * 128;
    const int col0 = blockIdx.y * 128;
    const int nk   = Kp >> 4;               // 19

    const bool isA = (tid < 128);
    const int  srow = isA ? tid : (tid - 128);
    const unsigned short* gh = isA ? (Ahi + (long)(row0 + srow)*Kp)
                                   : (Bhi + (long)(col0 + srow)*Kp);
    const unsigned short* gl = isA ? (Alo + (long)(row0 + srow)*Kp)
                                   : (Blo + (long)(col0 + srow)*Kp);
    const int stile = srow >> 5, slot = srow & 31;

    f32x16 acc[4];
    #pragma unroll
    for (int c = 0; c < 4; ++c) acc[c] = (f32x16)0.0f;

    u16x8 p0, p1, p2, p3, q0, q1, q2, q3;

    auto LOAD_P = [&](int t) {
        const unsigned short* ph = gh + t*16; const unsigned short* pl = gl + t*16;
        p0 = *(const u16x8*)ph; p1 = *(const u16x8*)(ph + 8);
        p2 = *(const u16x8*)pl; p3 = *(const u16x8*)(pl + 8);
    };
    auto LOAD_Q = [&](int t) {
        const unsigned short* ph = gh + t*16; const unsigned short* pl = gl + t*16;
        q0 = *(const u16x8*)ph; q1 = *(const u16x8*)(ph + 8);
        q2 = *(const u16x8*)pl; q3 = *(const u16x8*)(pl + 8);
    };

    #define WRITE_SET(a_, b_, c_, d_, buf_)                                        \
        {                                                                          \
            unsigned short* dh = isA ? &Ah[buf_][stile][slot][0]                   \
                                     : &Bh[buf_][stile][slot][0];                  \
            unsigned short* dl = isA ? &Al[buf_][stile][slot][0]                   \
                                     : &Bl[buf_][stile][slot][0];                  \
            *(u16x8*)dh = a_; *(u16x8*)(dh + 256) = b_;                            \
            *(u16x8*)dl = c_; *(u16x8*)(dl + 256) = d_;                            \
        }

    #define MFMA_STEP(buf_)                                                       \
        {                                                                          \
            u16x8 afh = *(const u16x8*)&Ah[buf_][wid][lane][0];                    \
            u16x8 afl = *(const u16x8*)&Al[buf_][wid][lane][0];                    \
            _Pragma("unroll")                                                      \
            for (int c = 0; c < 4; ++c) {                                          \
                u16x8 bfh = *(const u16x8*)&Bh[buf_][c][lane][0];                  \
                u16x8 bfl = *(const u16x8*)&Bl[buf_][c][lane][0];                  \
                MFMA32(acc[c], afh, bfh);                                          \
                MFMA32(acc[c], afl, bfh);                                          \
                MFMA32(acc[c], afh, bfl);                                          \
            }                                                                      \
        }

    // prologue: load k-steps 0,1; write 0 into buf0
    LOAD_P(0);
    LOAD_Q(1);
    WRITE_SET(p0, p1, p2, p3, 0);
    __syncthreads();

    int t = 0;
    for (;;) {
        // even step t: compute buf0; q holds t+1
        bool wr1 = (t + 1 < nk);
        if (t + 2 < nk) LOAD_P(t + 2);
        if (wr1) WRITE_SET(q0, q1, q2, q3, 1);
        MFMA_STEP(0);
        __syncthreads();
        if (!wr1) break;
        // odd step t+1: compute buf1; p holds t+2
        bool wr2 = (t + 2 < nk);
        if (t + 3 < nk) LOAD_Q(t + 3);
        if (wr2) WRITE_SET(p0, p1, p2, p3, 0);
        MFMA_STEP(1);
        __syncthreads();
        if (!wr2) break;
        t += 2;
    }
    #undef WRITE_SET
    #undef MFMA_STEP

    // epilogue: C/D layout col=lane&31, row=(reg&3)+8*(reg>>2)+4*(lane>>5)
    const int crow0 = row0 + wid*32 + 4*(lane >> 5);
    const int ccol0 = col0 + (lane & 31);
    #pragma unroll
    for (int c = 0; c < 4; ++c) {
        int col = ccol0 + c*32;
        if (col >= N) continue;
        #pragma unroll
        for (int reg = 0; reg < 16; ++reg) {
            int row = crow0 + (reg & 3) + 8*(reg >> 2);
            if (row < M) C[(long)row*ldc + col] = acc[c][reg];
        }
    }
}

// ---------- small f32 GEMM (tiny R x RH highway gate) ----------
#define GBM 64
#define GBN 64
#define GBK 16
__global__ __launch_bounds__(256)
void k_gemm(const float* __restrict__ A, long lda,
            const float* __restrict__ B, long ldb,
            float* __restrict__ C, long ldc,
            int M, int N, int K)
{
    __shared__ float As[GBK][GBM + 4];
    __shared__ float Bs[GBK][GBN + 4];
    const int tid = threadIdx.x;
    const int tx = tid & 15, ty = tid >> 4;
    const int row0 = blockIdx.y * GBM, col0 = blockIdx.x * GBN;
    float acc[4][4] = {};
    for (int kt = 0; kt < K; kt += GBK) {
        #pragma unroll
        for (int p = 0; p < 4; ++p) {
            int mn = (tid >> 4) + p * 16;
            int k  = tid & 15;
            int gk = kt + k;
            int gr = row0 + mn;
            As[k][mn] = (gr < M && gk < K) ? A[(long)gr * lda + gk] : 0.0f;
            int gc = col0 + mn;
            Bs[k][mn] = (gc < N && gk < K) ? B[(long)gc * ldb + gk] : 0.0f;
        }
        __syncthreads();
        #pragma unroll
        for (int kk = 0; kk < GBK; ++kk) {
            float a0 = As[kk][ty*4+0], a1 = As[kk][ty*4+1];
            float a2 = As[kk][ty*4+2], a3 = As[kk][ty*4+3];
            float b0 = Bs[kk][tx*4+0], b1 = Bs[kk][tx*4+1];
            float b2 = Bs[kk][tx*4+2], b3 = Bs[kk][tx*4+3];
            acc[0][0] += a0*b0; acc[0][1] += a0*b1; acc[0][2] += a0*b2; acc[0][3] += a0*b3;
            acc[1][0] += a1*b0; acc[1][1] += a1*b1; acc[1][2] += a1*b2; acc[1][3] += a1*b3;
            acc[2][0] += a2*b0; acc[2][1] += a2*b1; acc[2][2] += a2*b2; acc[2][3] += a2*b3;
            acc[3][0] += a3*b0; acc[3][1] += a3*b1; acc[3][2] += a3*b2; acc[3][3] += a3*b3;
        }
        __syncthreads();
    }
    #pragma unroll
    for (int i2 = 0; i2 < 4; ++i2)
        #pragma unroll
        for (int j2 = 0; j2 < 4; ++j2) {
            int r = row0 + ty*4 + i2, c = col0 + tx*4 + j2;
            if (r < M && c < N) C[(long)r*ldc + c] = acc[i2][j2];
        }
}

// ================= CSR build: histogram -> scan -> fill =================
__global__ void k_hist(const int* __restrict__ key, int* __restrict__ cnt, int E) {
    int e = blockIdx.x*blockDim.x + threadIdx.x;
    if (e < E) atomicAdd(&cnt[key[e]], 1);
}
__global__ void k_scan1(const int* __restrict__ in, int* __restrict__ out,
                        int* __restrict__ bsum, int n) {
    __shared__ int sh[256];
    int gid = blockIdx.x*256 + threadIdx.x;
    int v = (gid < n) ? in[gid] : 0;
    sh[threadIdx.x] = v; __syncthreads();
    for (int o = 1; o < 256; o <<= 1) {
        int t = (threadIdx.x >= o) ? sh[threadIdx.x - o] : 0;
        __syncthreads();
        sh[threadIdx.x] += t;
        __syncthreads();
    }
    if (gid < n) out[gid] = sh[threadIdx.x] - v;      // exclusive
    if (threadIdx.x == 255) bsum[blockIdx.x] = sh[255];
}
__global__ void k_scan2(int* __restrict__ bsum, int nb) {   // single block, nb <= 1024
    __shared__ int sh[1024];
    int v = (threadIdx.x < nb) ? bsum[threadIdx.x] : 0;
    sh[threadIdx.x] = v; __syncthreads();
    for (int o = 1; o < 1024; o <<= 1) {
        int t = (threadIdx.x >= o) ? sh[threadIdx.x - o] : 0;
        __syncthreads();
        sh[threadIdx.x] += t;
        __syncthreads();
    }
    if (threadIdx.x < nb) bsum[threadIdx.x] = sh[threadIdx.x] - v;  // exclusive
}
__global__ void k_scan3(int* __restrict__ out, const int* __restrict__ bsum, int n) {
    int gid = blockIdx.x*256 + threadIdx.x;
    if (gid < n) out[gid] += bsum[blockIdx.x];
}
__global__ void k_fill(const int* __restrict__ key, const int* __restrict__ rowptr,
                       int* __restrict__ cursor, int* __restrict__ perm, int E) {
    int e = blockIdx.x*blockDim.x + threadIdx.x;
    if (e >= E) return;
    int k = key[e];
    int p = rowptr[k] + atomicAdd(&cursor[k], 1);
    perm[p] = e;
}
__global__ void k_dinv_cnt(const int* __restrict__ cnt, float* __restrict__ dinv, int n) {
    int i = blockIdx.x*blockDim.x + threadIdx.x;
    if (i < n) { int c = cnt[i]; dinv[i] = (c > 0) ? rsqrtf((float)c) : 0.0f; }
}

// ---------- CSR-order pre-permutation ----------
__global__ void k_prep_gcn(const int* __restrict__ perm, const int* __restrict__ jA,
                           const int* __restrict__ iA, const float* __restrict__ dinv,
                           int* __restrict__ jp, float* __restrict__ nm, int E) {
    int p = blockIdx.x*blockDim.x + threadIdx.x;
    if (p >= E) return;
    int e = perm[p];
    int j = jA[e];
    jp[p] = j;
    nm[p] = dinv[iA[e]] * dinv[j];
}
__global__ void k_permute_i32(const int* __restrict__ src, const int* __restrict__ perm,
                              int* __restrict__ dst, int E) {
    int p = blockIdx.x*blockDim.x + threadIdx.x;
    if (p < E) dst[p] = src[perm[p]];
}
__global__ void k_permute_mod(const int* __restrict__ src, const int* __restrict__ perm,
                              int* __restrict__ dst, int E, int mod) {
    int p = blockIdx.x*blockDim.x + threadIdx.x;
    if (p < E) dst[p] = src[perm[p]] % mod;
}

// ============ gather aggregations (wave per destination node, F=300) ============
__global__ void k_gather300(const float* __restrict__ x, long ldx,
                            const int* __restrict__ jp, const float* __restrict__ nm,
                            const int* __restrict__ rowptr, const int* __restrict__ cnt,
                            float* __restrict__ out, long ldo, int n)
{
    int w = (blockIdx.x*blockDim.x + threadIdx.x) >> 6;
    int lane = threadIdx.x & 63;
    if (w >= n) return;
    int beg = rowptr[w], end = beg + cnt[w];
    const int i0 = lane, i1 = lane + 64, i2 = lane + 128;
    const bool t3 = (lane < 22);
    float2 a0 = {0,0}, a1 = {0,0}, a2 = {0,0};
    int e = beg;
    for (; e + 4 <= end; e += 4) {
        const float2* r0 = (const float2*)(x + (long)jp[e]  *ldx);
        const float2* r1 = (const float2*)(x + (long)jp[e+1]*ldx);
        const float2* r2 = (const float2*)(x + (long)jp[e+2]*ldx);
        const float2* r3 = (const float2*)(x + (long)jp[e+3]*ldx);
        float w0 = nm[e], w1 = nm[e+1], w2 = nm[e+2], w3 = nm[e+3];
        float2 v;
        v = r0[i0]; a0.x += w0*v.x; a0.y += w0*v.y;
        v = r1[i0]; a0.x += w1*v.x; a0.y += w1*v.y;
        v = r2[i0]; a0.x += w2*v.x; a0.y += w2*v.y;
        v = r3[i0]; a0.x += w3*v.x; a0.y += w3*v.y;
        v = r0[i1]; a1.x += w0*v.x; a1.y += w0*v.y;
        v = r1[i1]; a1.x += w1*v.x; a1.y += w1*v.y;
        v = r2[i1]; a1.x += w2*v.x; a1.y += w2*v.y;
        v = r3[i1]; a1.x += w3*v.x; a1.y += w3*v.y;
        if (t3) {
            v = r0[i2]; a2.x += w0*v.x; a2.y += w0*v.y;
            v = r1[i2]; a2.x += w1*v.x; a2.y += w1*v.y;
            v = r2[i2]; a2.x += w2*v.x; a2.y += w2*v.y;
            v = r3[i2]; a2.x += w3*v.x; a2.y += w3*v.y;
        }
    }
    for (; e < end; ++e) {
        const float2* r0 = (const float2*)(x + (long)jp[e]*ldx);
        float w0 = nm[e];
        float2 v;
        v = r0[i0]; a0.x += w0*v.x; a0.y += w0*v.y;
        v = r0[i1]; a1.x += w0*v.x; a1.y += w0*v.y;
        if (t3) { v = r0[i2]; a2.x += w0*v.x; a2.y += w0*v.y; }
    }
    float2* dst = (float2*)(out + (long)w*ldo);
    dst[i0] = a0; dst[i1] = a1;
    if (t3) dst[i2] = a2;
}

// GAT: fused edge score + segment softmax + weighted gather + relu (F=300)
__global__ void k_gat300(const float* __restrict__ x, long ldx,
                         const float* __restrict__ sA, const float* __restrict__ sB,
                         const float* __restrict__ rsc,
                         const int* __restrict__ jp, const int* __restrict__ relp,
                         const int* __restrict__ rowptr, const int* __restrict__ cnt,
                         float* __restrict__ out, long ldo, int n)
{
    int w = (blockIdx.x*blockDim.x + threadIdx.x) >> 6;
    int lane = threadIdx.x & 63;
    if (w >= n) return;
    int beg = rowptr[w], c = cnt[w];
    const int i0 = lane, i1 = lane + 64, i2 = lane + 128;
    const bool t3 = (lane < 22);
    float2 a0 = {0,0}, a1 = {0,0}, a2 = {0,0};
    if (c > 0) {
        float base = sA[w];
        int   jc = 0;
        float sval = -3.4e38f;
        if (lane < c) {
            jc = jp[beg + lane];
            sval = leaky(base + sB[jc] + rsc[relp[beg + lane]]);
        }
        float mx = sval;
        for (int t = 64 + lane; t < c; t += 64)
            mx = fmaxf(mx, leaky(base + sB[jp[beg+t]] + rsc[relp[beg+t]]));
        #pragma unroll
        for (int o = 32; o > 0; o >>= 1) mx = fmaxf(mx, __shfl_xor(mx, o));
        float pexp = (lane < c) ? expf(sval - mx) : 0.0f;
        float ss = pexp;
        for (int t = 64 + lane; t < c; t += 64)
            ss += expf(leaky(base + sB[jp[beg+t]] + rsc[relp[beg+t]]) - mx);
        #pragma unroll
        for (int o = 32; o > 0; o >>= 1) ss += __shfl_xor(ss, o);
        float inv = 1.0f / (ss + 1e-16f);
        int q = 0;
        int cc = (c < 64) ? c : 64;
        for (; q + 4 <= cc; q += 4) {
            float al0 = __shfl(pexp, q)   * inv;
            float al1 = __shfl(pexp, q+1) * inv;
            float al2 = __shfl(pexp, q+2) * inv;
            float al3 = __shfl(pexp, q+3) * inv;
            long  j0 = __shfl(jc, q), j1 = __shfl(jc, q+1);
            long  j2 = __shfl(jc, q+2), j3 = __shfl(jc, q+3);
            const float2* r0 = (const float2*)(x + j0*ldx);
            const float2* r1 = (const float2*)(x + j1*ldx);
            const float2* r2 = (const float2*)(x + j2*ldx);
            const float2* r3 = (const float2*)(x + j3*ldx);
            float2 v;
            v = r0[i0]; a0.x += al0*v.x; a0.y += al0*v.y;
            v = r1[i0]; a0.x += al1*v.x; a0.y += al1*v.y;
            v = r2[i0]; a0.x += al2*v.x; a0.y += al2*v.y;
            v = r3[i0]; a0.x += al3*v.x; a0.y += al3*v.y;
            v = r0[i1]; a1.x += al0*v.x; a1.y += al0*v.y;
            v = r1[i1]; a1.x += al1*v.x; a1.y += al1*v.y;
            v = r2[i1]; a1.x += al2*v.x; a1.y += al2*v.y;
            v = r3[i1]; a1.x += al3*v.x; a1.y += al3*v.y;
            if (t3) {
                v = r0[i2]; a2.x += al0*v.x; a2.y += al0*v.y;
                v = r1[i2]; a2.x += al1*v.x; a2.y += al1*v.y;
                v = r2[i2]; a2.x += al2*v.x; a2.y += al2*v.y;
                v = r3[i2]; a2.x += al3*v.x; a2.y += al3*v.y;
            }
        }
        for (; q < c; ++q) {
            float al; long j0;
            if (q < 64) { al = __shfl(pexp, q) * inv; j0 = __shfl(jc, q); }
            else {
                j0 = jp[beg + q];
                al = expf(leaky(base + sB[(int)j0] + rsc[relp[beg+q]]) - mx) * inv;
            }
            const float2* r0 = (const float2*)(x + j0*ldx);
            float2 v;
            v = r0[i0]; a0.x += al*v.x; a0.y += al*v.y;
            v = r0[i1]; a1.x += al*v.x; a1.y += al*v.y;
            if (t3) { v = r0[i2]; a2.x += al*v.x; a2.y += al*v.y; }
        }
    }
    float2* dst = (float2*)(out + (long)w*ldo);
    a0.x = fmaxf(a0.x, 0.0f); a0.y = fmaxf(a0.y, 0.0f);
    a1.x = fmaxf(a1.x, 0.0f); a1.y = fmaxf(a1.y, 0.0f);
    dst[i0] = a0; dst[i1] = a1;
    if (t3) { a2.x = fmaxf(a2.x, 0.0f); a2.y = fmaxf(a2.y, 0.0f); dst[i2] = a2; }
}

// r2e: fused score = leaky(snode[w] + srel[relp]) + softmax + gather of xr (F=100)
__global__ void k_gather_rel100(const float* __restrict__ xr,
                                const float* __restrict__ snode,
                                const float* __restrict__ srel,
                                const int* __restrict__ relp,
                                const int* __restrict__ rowptr, const int* __restrict__ cnt,
                                float* __restrict__ out, long ldo, int n)
{
    int w = (blockIdx.x*blockDim.x + threadIdx.x) >> 6;
    int lane = threadIdx.x & 63;
    if (w >= n) return;
    int beg = rowptr[w], c = cnt[w];
    const bool t0 = (lane < 50);
    float2 a0 = {0,0};
    if (c > 0) {
        float base = snode[w];
        int   rc = 0;
        float sval = -3.4e38f;
        if (lane < c) {
            rc = relp[beg + lane];
            sval = leaky(base + srel[rc]);
        }
        float mx = sval;
        for (int t = 64 + lane; t < c; t += 64)
            mx = fmaxf(mx, leaky(base + srel[relp[beg+t]]));
        #pragma unroll
        for (int o = 32; o > 0; o >>= 1) mx = fmaxf(mx, __shfl_xor(mx, o));
        float pexp = (lane < c) ? expf(sval - mx) : 0.0f;
        float ss = pexp;
        for (int t = 64 + lane; t < c; t += 64)
            ss += expf(leaky(base + srel[relp[beg+t]]) - mx);
        #pragma unroll
        for (int o = 32; o > 0; o >>= 1) ss += __shfl_xor(ss, o);
        float inv = 1.0f / (ss + 1e-16f);
        int q = 0;
        int cc = (c < 64) ? c : 64;
        for (; q + 4 <= cc; q += 4) {
            float al0 = __shfl(pexp, q)   * inv;
            float al1 = __shfl(pexp, q+1) * inv;
            float al2 = __shfl(pexp, q+2) * inv;
            float al3 = __shfl(pexp, q+3) * inv;
            long r0i = __shfl(rc, q), r1i = __shfl(rc, q+1);
            long r2i = __shfl(rc, q+2), r3i = __shfl(rc, q+3);
            if (t0) {
                float2 v;
                v = ((const float2*)(xr + r0i*100))[lane]; a0.x += al0*v.x; a0.y += al0*v.y;
                v = ((const float2*)(xr + r1i*100))[lane]; a0.x += al1*v.x; a0.y += al1*v.y;
                v = ((const float2*)(xr + r2i*100))[lane]; a0.x += al2*v.x; a0.y += al2*v.y;
                v = ((const float2*)(xr + r3i*100))[lane]; a0.x += al3*v.x; a0.y += al3*v.y;
            }
        }
        for (; q < c; ++q) {
            float al; long r0i;
            if (q < 64) { al = __shfl(pexp, q) * inv; r0i = __shfl(rc, q); }
            else {
                r0i = relp[beg + q];
                al = expf(leaky(base + srel[(int)r0i]) - mx) * inv;
            }
            if (t0) {
                float2 v = ((const float2*)(xr + r0i*100))[lane];
                a0.x += al*v.x; a0.y += al*v.y;
            }
        }
    }
    if (t0) ((float2*)(out + (long)w*ldo))[lane] = a0;
}

// ---------- highway combine ----------
__global__ void k_highway(const float* __restrict__ x1, long ld1,
                          const float* __restrict__ gl, long ldg,
                          const float* __restrict__ x2, long ld2,
                          const float* __restrict__ bias,
                          float* __restrict__ out, long ldo,
                          long rows, int F, int relu_x2)
{
    long idx = (long)blockIdx.x*blockDim.x + threadIdx.x;
    if (idx >= rows * (long)F) return;
    long r = idx / F; int c = (int)(idx % F);
    float g = 1.0f / (1.0f + expf(-(gl[r*ldg+c] + bias[c])));
    float v2 = x2[r*ld2+c]; if (relu_x2) v2 = fmaxf(v2, 0.0f);
    float v1 = x1[r*ld1+c];
    out[r*ldo+c] = g*v2 + (1.0f-g)*v1;
}

// ---------- segment softmax building blocks (small l_gat path only) ----------
__global__ void k_segmax(const float* __restrict__ ev, const int* __restrict__ idx,
                         unsigned* __restrict__ m, int E) {
    int e = blockIdx.x*blockDim.x + threadIdx.x;
    if (e < E) atomicMax(&m[idx[e]], f2mono(ev[e]));
}
__global__ void k_segsumexp(const float* __restrict__ ev, const int* __restrict__ idx,
                            const unsigned* __restrict__ m, float* __restrict__ s, int E) {
    int e = blockIdx.x*blockDim.x + threadIdx.x;
    if (e < E) atomicAdd(&s[idx[e]], expf(ev[e] - mono2f(m[idx[e]])));
}
__global__ void k_lgat_vsum(const float* __restrict__ val,
                            const int* __restrict__ jj, const int* __restrict__ ii,
                            const unsigned* __restrict__ mi, const float* __restrict__ si,
                            const unsigned* __restrict__ mj, const float* __restrict__ sj,
                            float* __restrict__ vsum, int E)
{
    int e = blockIdx.x*blockDim.x + threadIdx.x;
    if (e >= E) return;
    float v = val[e];
    int i = ii[e], j = jj[e];
    float pi = expf(v - mono2f(mi[i])) / (si[i] + 1e-16f);
    float pj = expf(v - mono2f(mj[j])) / (sj[j] + 1e-16f);
    vsum[e] = pi + pj;
}
__global__ void k_edge_agg(const float* __restrict__ ev,
                           const unsigned* __restrict__ m, const float* __restrict__ s,
                           const int* __restrict__ ka, const int* __restrict__ ko,
                           const int* __restrict__ ks,
                           const float* __restrict__ x, long ldx,
                           float* __restrict__ out, long ldo,
                           int E, int F)
{
    int w = (blockIdx.x*blockDim.x + threadIdx.x) >> 6;
    int lane = threadIdx.x & 63;
    if (w >= E) return;
    int a = ka[w];
    float alpha = expf(ev[w] - mono2f(m[a])) / (s[a] + 1e-16f);
    const float4* src = (const float4*)(x + (long)ks[w]*ldx);
    float* dst = out + (long)ko[w]*ldo;
    int nf4 = F >> 2;
    for (int f = lane; f < nf4; f += WAVE) {
        float4 v = src[f];
        atomicAdd(&dst[f*4+0], alpha*v.x);
        atomicAdd(&dst[f*4+1], alpha*v.y);
        atomicAdd(&dst[f*4+2], alpha*v.z);
        atomicAdd(&dst[f*4+3], alpha*v.w);
    }
}
__global__ void k_relu2d(float* __restrict__ p, long rows, int cols, long ld) {
    long idx = (long)blockIdx.x*blockDim.x + threadIdx.x;
    if (idx >= rows*(long)cols) return;
    long r = idx / cols; int c = (int)(idx % cols);
    float v = p[r*ld+c];
    p[r*ld+c] = fmaxf(v, 0.0f);
}

// ---------- row dots ----------
__global__ void k_rowdot2(const float* __restrict__ x, long ldx, int rows, int K,
                          const float* __restrict__ a, const float* __restrict__ b,
                          float* __restrict__ oa, float* __restrict__ ob)
{
    int w = (blockIdx.x*blockDim.x + threadIdx.x) >> 6;
    int lane = threadIdx.x & 63;
    if (w >= rows) return;
    const float* xr = x + (long)w*ldx;
    float sa = 0.0f, sb = 0.0f;
    for (int k = lane; k < K; k += WAVE) {
        float v = xr[k];
        sa += v * a[k];
        if (b) sb += v * b[k];
    }
    #pragma unroll
    for (int off = 32; off > 0; off >>= 1) {
        sa += __shfl_down(sa, off);
        if (b) sb += __shfl_down(sb, off);
    }
    if (lane == 0) { oa[w] = sa; if (ob) ob[w] = sb; }
}

// ---------- relscore[r] = merge[r]·ar[0:RH] + tri[r]·ar[RH:2RH] ----------
__global__ void k_relscore(const float* __restrict__ mg, const float* __restrict__ tr,
                           const float* __restrict__ ar, float* __restrict__ out, int R, int RH)
{
    int w = (blockIdx.x*blockDim.x + threadIdx.x) >> 6;
    int lane = threadIdx.x & 63;
    if (w >= R) return;
    float s = 0.0f;
    for (int k = lane; k < RH; k += WAVE)
        s += mg[(long)w*RH+k]*ar[k] + tr[(long)w*RH+k]*ar[RH+k];
    #pragma unroll
    for (int off = 32; off > 0; off >>= 1) s += __shfl_down(s, off);
    if (lane == 0) out[w] = s;
}

extern "C" void kernel_launch(void* const* d_in, const int* in_sizes, int n_in,
                              void* d_out, int out_size, void* d_ws, size_t ws_size,
                              hipStream_t stream)
{
    const float* x_e   = (const float*)d_in[0];
    const float* mval  = (const float*)d_in[1];
    const float* tval  = (const float*)d_in[2];
    const float* g1w   = (const float*)d_in[3];
    const float* h1w   = (const float*)d_in[4];
    const float* h1b   = (const float*)d_in[5];
    const float* g2w   = (const float*)d_in[6];
    const float* h2w   = (const float*)d_in[7];
    const float* h2b   = (const float*)d_in[8];
    const float* remb1 = (const float*)d_in[9];
    const float* remb2 = (const float*)d_in[10];
    const float* hrw   = (const float*)d_in[11];
    const float* hrb   = (const float*)d_in[12];
    const float* gat_ai= (const float*)d_in[13];
    const float* gat_aj= (const float*)d_in[14];
    const float* gat_ar= (const float*)d_in[15];
    const float* g2e_ah= (const float*)d_in[16];
    const float* g2e_at= (const float*)d_in[17];
    const float* g2e_ar= (const float*)d_in[18];
    const int* edge_index     = (const int*)d_in[19];
    const int* rel            = (const int*)d_in[20];
    const int* edge_index_all = (const int*)d_in[21];
    const int* rel_all        = (const int*)d_in[22];
    const int* lg_merge       = (const int*)d_in[23];
    const int* lg_tri         = (const int*)d_in[24];

    const int F    = 300;
    const int RH   = 100;
    const int Kp   = 304;                  // padded K for bf16 arrays
    const int N    = in_sizes[0] / F;      // 100000
    const int E    = in_sizes[20];         // 400000
    const int EA   = in_sizes[22];         // 800000
    const int LGE  = in_sizes[1];          // 60000
    const int R    = in_sizes[9] / RH;     // 2000
    const long OUTC = 800;
    const int Mpad = CDIV(N, 128) * 128;   // 100096
    const int Npad = 384;                  // 3 col-blocks of 128

    const int* jA = edge_index_all;
    const int* iA = edge_index_all + EA;
    const int* hE = edge_index;
    const int* tE = edge_index + E;
    const int* jM = lg_merge;  const int* iM = lg_merge + LGE;
    const int* jT = lg_tri;    const int* iT = lg_tri  + LGE;

    float* ws = (float*)d_ws;
    size_t off = 0;
    auto alloc = [&](size_t n) { float* p = ws + off; off += (n + 3) & ~(size_t)3; return p; };
    float*    Ascr = alloc((size_t)N*F);                       // GEMM output scratch f32
    unsigned short* Axh = (unsigned short*)alloc((size_t)Mpad*Kp/2);  // A bf16 hi
    unsigned short* Axl = (unsigned short*)alloc((size_t)Mpad*Kp/2);  // A bf16 lo
    unsigned short* Wh[4]; unsigned short* Wl[4];
    for (int i = 0; i < 4; ++i) {
        Wh[i] = (unsigned short*)alloc((size_t)Npad*Kp/2);
        Wl[i] = (unsigned short*)alloc((size_t)Npad*Kp/2);
    }
    float*    dinv = alloc(N);
    float*    sA_  = alloc(N);
    float*    sB_  = alloc(N);
    float*    mrg  = alloc((size_t)R*RH);
    float*    tri  = alloc((size_t)R*RH);
    float*    xr   = alloc((size_t)R*RH);
    float*    xrg  = alloc((size_t)R*RH);
    unsigned* lmi  = (unsigned*)alloc(R);  float* lsi = alloc(R);
    unsigned* lmj  = (unsigned*)alloc(R);  float* lsj = alloc(R);
    unsigned* lm2  = (unsigned*)alloc(R);  float* ls2 = alloc(R);
    float*    vsum = alloc(LGE);
    float*    rsc  = alloc(R);
    float*    srel = alloc(R);
    int*   bsum    = (int*)alloc(1024);
    int*   cursor  = (int*)alloc(N);
    int*   rowptrA = (int*)alloc(N); int* cntA = (int*)alloc(N); int* permA = (int*)alloc(EA);
    int*   rowptrH = (int*)alloc(N); int* cntH = (int*)alloc(N); int* permH = (int*)alloc(E);
    int*   rowptrT = (int*)alloc(N); int* cntT = (int*)alloc(N); int* permT = (int*)alloc(E);
    int*   jpA     = (int*)alloc(EA);
    float* nmA     = alloc(EA);
    int*   relpA   = (int*)alloc(EA);
    int*   relpH   = (int*)alloc(E);
    int*   relpT   = (int*)alloc(E);

    float* out = (float*)d_out;              // [N, 800]

    const long NF = (long)N * F;
    const int  nb = CDIV(N, 256);
    dim3 gemmGrid(CDIV(N, 128), 3);          // 782 x 3 col-blocks
    const int gatherGrid = CDIV(N, 4);
    const int cvtBigGrid = CDIV((long)N * (Kp/4), 256);
    const int cvtWGrid   = CDIV(300 * (Kp/4), 256);

    auto build_csr = [&](const int* key, int E_, int* rowptr, int* cnt, int* perm) {
        hipMemsetAsync(cnt, 0, (size_t)N*4, stream);
        k_hist<<<CDIV(E_,256),256,0,stream>>>(key, cnt, E_);
        k_scan1<<<nb,256,0,stream>>>(cnt, rowptr, bsum, N);
        k_scan2<<<1,1024,0,stream>>>(bsum, nb);
        k_scan3<<<nb,256,0,stream>>>(rowptr, bsum, N);
        hipMemsetAsync(cursor, 0, (size_t)N*4, stream);
        k_fill<<<CDIV(E_,256),256,0,stream>>>(key, rowptr, cursor, perm, E_);
    };

    // ===== weight + x_e converts (independent, run first) =====
    k_cvt<<<cvtWGrid,256,0,stream>>>(g1w, 300, 300, 300, Kp, Wh[0], Wl[0]);
    k_cvt<<<cvtWGrid,256,0,stream>>>(h1w, 300, 300, 300, Kp, Wh[1], Wl[1]);
    k_cvt<<<cvtWGrid,256,0,stream>>>(g2w, 300, 300, 300, Kp, Wh[2], Wl[2]);
    k_cvt<<<cvtWGrid,256,0,stream>>>(h2w, 300, 300, 300, Kp, Wh[3], Wl[3]);
    k_cvt<<<cvtBigGrid,256,0,stream>>>(x_e, 300, N, 300, Kp, Axh, Axl);

    // ===== CSRs + pre-permutes =====
    build_csr(iA, EA, rowptrA, cntA, permA);
    build_csr(hE, E,  rowptrH, cntH, permH);
    build_csr(tE, E,  rowptrT, cntT, permT);
    k_dinv_cnt<<<CDIV(N,256),256,0,stream>>>(cntA, dinv, N);
    k_prep_gcn<<<CDIV(EA,256),256,0,stream>>>(permA, jA, iA, dinv, jpA, nmA, EA);
    k_permute_mod<<<CDIV(EA,256),256,0,stream>>>(rel_all, permA, relpA, EA, R);
    k_permute_i32<<<CDIV(E,256),256,0,stream>>>(rel, permH, relpH, E);
    k_permute_i32<<<CDIV(E,256),256,0,stream>>>(rel, permT, relpT, E);

    // ===== GCN layer 1 + highway =====
    k_gemm_pre<<<gemmGrid,256,0,stream>>>(Axh, Axl, Wh[0], Wl[0], Ascr, F, N, F, Kp);
    k_gather300<<<gatherGrid,256,0,stream>>>(Ascr, F, jpA, nmA, rowptrA, cntA, out+300, OUTC, N);
    k_gemm_pre<<<gemmGrid,256,0,stream>>>(Axh, Axl, Wh[1], Wl[1], Ascr, F, N, F, Kp);
    k_highway<<<CDIV(NF,256),256,0,stream>>>(x_e, F, Ascr, F, out+300, OUTC, h1b, out, OUTC, N, F, 1);

    // ===== GCN layer 2 + highway =====
    k_cvt<<<cvtBigGrid,256,0,stream>>>(out, OUTC, N, 300, Kp, Axh, Axl);
    k_gemm_pre<<<gemmGrid,256,0,stream>>>(Axh, Axl, Wh[2], Wl[2], Ascr, F, N, F, Kp);
    k_gather300<<<gatherGrid,256,0,stream>>>(Ascr, F, jpA, nmA, rowptrA, cntA, out+300, OUTC, N);
    k_gemm_pre<<<gemmGrid,256,0,stream>>>(Axh, Axl, Wh[3], Wl[3], Ascr, F, N, F, Kp);
    k_highway<<<CDIV(NF,256),256,0,stream>>>(out, OUTC, Ascr, F, out+300, OUTC, h2b, out, OUTC, N, F, 1);

    // ===== l_gat on the two line graphs (small; atomic path) =====
    auto lgat = [&](const float* xrel, const int* jjE, const int* iiE, const float* val, float* obuf) {
        hipMemsetAsync(lmi, 0, R*4, stream); hipMemsetAsync(lsi, 0, R*4, stream);
        hipMemsetAsync(lmj, 0, R*4, stream); hipMemsetAsync(lsj, 0, R*4, stream);
        hipMemsetAsync(lm2, 0, R*4, stream); hipMemsetAsync(ls2, 0, R*4, stream);
        hipMemsetAsync(obuf, 0, (size_t)R*RH*4, stream);
        k_segmax   <<<CDIV(LGE,256),256,0,stream>>>(val, iiE, lmi, LGE);
        k_segmax   <<<CDIV(LGE,256),256,0,stream>>>(val, jjE, lmj, LGE);
        k_segsumexp<<<CDIV(LGE,256),256,0,stream>>>(val, iiE, lmi, lsi, LGE);
        k_segsumexp<<<CDIV(LGE,256),256,0,stream>>>(val, jjE, lmj, lsj, LGE);
        k_lgat_vsum<<<CDIV(LGE,256),256,0,stream>>>(val, jjE, iiE, lmi, lsi, lmj, lsj, vsum, LGE);
        k_segmax   <<<CDIV(LGE,256),256,0,stream>>>(vsum, jjE, lm2, LGE);
        k_segsumexp<<<CDIV(LGE,256),256,0,stream>>>(vsum, jjE, lm2, ls2, LGE);
        k_edge_agg <<<(int)CDIV((long)LGE*64,256),256,0,stream>>>(vsum, lm2, ls2, jjE, iiE, jjE,
                                                                  xrel, RH, obuf, RH, LGE, RH);
        k_relu2d   <<<CDIV((long)R*RH,256),256,0,stream>>>(obuf, R, RH, RH);
    };
    lgat(remb1, jM, iM, mval, mrg);
    lgat(remb2, jT, iT, tval, tri);

    // ===== x_r = highway(mrg, tri, hrw, hrb) =====
    dim3 gridR(CDIV(RH,GBN), CDIV(R,GBM));
    k_gemm<<<gridR,256,0,stream>>>(mrg, RH, hrw, RH, xrg, RH, R, RH, RH);
    k_highway<<<CDIV((long)R*RH,256),256,0,stream>>>(mrg, RH, xrg, RH, tri, RH, hrb, xr, RH, R, RH, 0);

    // relscore[r] = rel_cat[r]·gat_ar
    k_relscore<<<CDIV((long)R*64,256),256,0,stream>>>(mrg, tri, gat_ar, rsc, R, RH);

    // ===== GAT over edge_index_all -> out cols 300..599 (fully fused) =====
    k_rowdot2<<<CDIV((long)N*64,256),256,0,stream>>>(out, OUTC, N, F, gat_ai, gat_aj, sA_, sB_);
    k_gat300<<<gatherGrid,256,0,stream>>>(out, OUTC, sA_, sB_, rsc, jpA, relpA,
                                          rowptrA, cntA, out+300, OUTC, N);

    // ===== gat_r_to_e over edge_index -> out cols 600..799 (fully fused) =====
    k_rowdot2<<<CDIV((long)N*64,256),256,0,stream>>>(out, OUTC, N, 2*F, g2e_ah, g2e_at, sA_, sB_);
    k_rowdot2<<<CDIV((long)R*64,256),256,0,stream>>>(xr, RH, R, RH, g2e_ar, (const float*)nullptr,
                                                     srel, (float*)nullptr);
    k_gather_rel100<<<gatherGrid,256,0,stream>>>(xr, sA_, srel, relpH, rowptrH, cntH,
                                                 out+600, OUTC, N);
    k_gather_rel100<<<gatherGrid,256,0,stream>>>(xr, sB_, srel, relpT, rowptrT, cntT,
                                                 out+700, OUTC, N);
}